// Round 3
// baseline (371.565 us; speedup 1.0000x reference)
//
#include <hip/hip_runtime.h>
#include <hip/hip_bf16.h>
#include <hip/hip_cooperative_groups.h>

namespace cg = cooperative_groups;

typedef unsigned short u16;
typedef __attribute__((ext_vector_type(8))) short short8;   // 8 bf16 = 4 VGPRs
typedef __attribute__((ext_vector_type(4))) float f32x4;

#define BATCH 64
#define SEQ   256
#define CDIM  384
#define NHEAD 6
#define DHEAD 64
#define NROW  16384   // BATCH*SEQ

constexpr float SCALE = 0.051031036307982884f;  // 384^-0.5

__device__ __forceinline__ f32x4 mfma16(short8 a, short8 b, f32x4 c) {
    return __builtin_amdgcn_mfma_f32_16x16x32_bf16(a, b, c, 0, 0, 0);
}

__device__ __forceinline__ u16 f2b(float f) {
    __hip_bfloat16 h = __float2bfloat16(f);
    return *reinterpret_cast<u16*>(&h);
}

__device__ __forceinline__ void gload_lds16(const u16* g, u16* l) {
    __builtin_amdgcn_global_load_lds(
        (const __attribute__((address_space(1))) void*)g,
        (__attribute__((address_space(3))) void*)l, 16, 0, 0);
}

// ===========================================================================
// Phase bodies (shared between the fused cooperative kernel and the 4-kernel
// fallback path). Identical computation to the verified R2 kernels.
// ===========================================================================

// ---- phase 1: fp32 -> bf16 for x and the 4 weights ------------------------
__device__ __forceinline__ void cvt_body(
        int blk,
        const float* __restrict__ x,
        const float* __restrict__ Wk, const float* __restrict__ Wq,
        const float* __restrict__ Wv, const float* __restrict__ Wo,
        u16* __restrict__ xb,
        u16* __restrict__ wkb, u16* __restrict__ wqb,
        u16* __restrict__ wvb, u16* __restrict__ wob)
{
    const float* s;
    u16* d;
    if (blk < 3072) {
        s = x; d = xb;
    } else {
        const int w = blk - 3072;
        const int z = w / 72;           // 0..3
        blk = w - z * 72;
        s = (z == 0) ? Wk : (z == 1) ? Wq : (z == 2) ? Wv : Wo;
        d = (z == 0) ? wkb : (z == 1) ? wqb : (z == 2) ? wvb : wob;
    }
    const int i = (blk * 256 + (int)threadIdx.x) * 8;
    const float4 a = *(const float4*)(s + i);
    const float4 b = *(const float4*)(s + i + 4);
    short8 r;
    r[0] = (short)f2b(a.x); r[1] = (short)f2b(a.y);
    r[2] = (short)f2b(a.z); r[3] = (short)f2b(a.w);
    r[4] = (short)f2b(b.x); r[5] = (short)f2b(b.y);
    r[6] = (short)f2b(b.z); r[7] = (short)f2b(b.w);
    *(short8*)(d + i) = r;
}

// ---- phase 2: QKV projection Y = X @ W^T, 128x128 tile, BK=64 -------------
// z=0: K -> [B,H,T,D]; z=1: V^T -> [B,H,D,T]; z=2: Q -> [B,H,T,D]
__device__ __forceinline__ void qkv_body(
        int n0, int m0, int z, u16* SMEM,
        const u16* __restrict__ X, const u16* __restrict__ Wk,
        const u16* __restrict__ Wv, const u16* __restrict__ Wq,
        u16* __restrict__ Kd, u16* __restrict__ VTd, u16* __restrict__ Qd)
{
    u16* As = SMEM;
    u16* Bs = SMEM + 8192;
    const u16* W = (z == 0) ? Wk : (z == 1 ? Wv : Wq);

    const int tid  = threadIdx.x;
    const int lane = tid & 63;
    const int wv   = tid >> 6;
    const int l15  = lane & 15;
    const int q4   = lane >> 4;
    const int wm   = (wv >> 1) * 64;
    const int wn   = (wv & 1) * 64;

    f32x4 acc[4][4] = {};

    for (int kk = 0; kk < CDIM; kk += 64) {
        __syncthreads();   // previous iteration's LDS readers done
#pragma unroll
        for (int ch = 0; ch < 4; ++ch) {
            const int f = (ch * 256 + tid) * 8;   // linear LDS elem index
            const int r = f >> 6;
            const int c = (f ^ ((r & 7) << 3)) & 63;
            const int lb = (ch * 256 + wv * 64) * 8;   // wave-uniform LDS base
            gload_lds16(X + (size_t)(m0 + r) * CDIM + kk + c, As + lb);
            gload_lds16(W + (size_t)(n0 + r) * CDIM + kk + c, Bs + lb);
        }
        __syncthreads();   // staging complete (vmcnt drained by barrier)

#pragma unroll
        for (int ks = 0; ks < 2; ++ks) {
            short8 af[4], bf[4];
#pragma unroll
            for (int t = 0; t < 4; ++t) {
                const int ra = wm + t * 16 + l15;
                const int rb = wn + t * 16 + l15;
                af[t] = *(const short8*)(As + ra * 64 +
                        ((ks * 32 + q4 * 8) ^ ((ra & 7) << 3)));
                bf[t] = *(const short8*)(Bs + rb * 64 +
                        ((ks * 32 + q4 * 8) ^ ((rb & 7) << 3)));
            }
#pragma unroll
            for (int tm = 0; tm < 4; ++tm)
#pragma unroll
                for (int tn = 0; tn < 4; ++tn)
                    acc[tm][tn] = mfma16(af[tm], bf[tn], acc[tm][tn]);
        }
    }
    __syncthreads();   // all waves done with As/Bs; SMEM free for epilogue

    if (z != 1) {
        // ---- coalesced epilogue to [B,H,T,D] via LDS --------------------
        u16* D = (z == 0) ? Kd : Qd;
        u16* T = SMEM;                    // [128 t][128 col], XOR chunk-swz
#pragma unroll
        for (int tm = 0; tm < 4; ++tm)
#pragma unroll
            for (int tn = 0; tn < 4; ++tn) {
                const int cl = wn + tn * 16 + l15;
#pragma unroll
                for (int r = 0; r < 4; ++r) {
                    const int row = wm + tm * 16 + q4 * 4 + r;
                    T[row * 128 + (((cl >> 3) ^ (row & 7)) << 3) + (cl & 7)] =
                        f2b(acc[tm][tn][r]);
                }
            }
        __syncthreads();
        const int seg0 = tid >> 3;        // 0..31
        const int c    = tid & 7;         // 16B chunk within 64-d segment
#pragma unroll
        for (int it = 0; it < 8; ++it) {
            const int S   = it * 32 + seg0;   // 0..255: (row, head-half)
            const int row = S >> 1;
            const int hf  = S & 1;
            const int rowg = m0 + row;
            const int b  = rowg >> 8, tt = rowg & 255;
            const int h  = (n0 + hf * 64) >> 6;
            const int chunk = (hf * 8 + c) ^ (row & 7);
            *(uint4*)(D + (size_t)((b * NHEAD + h) * SEQ + tt) * DHEAD + c * 8) =
                *(const uint4*)(T + row * 128 + chunk * 8);
        }
    } else {
        // ---- transpose epilogue: V^T [B,H,D,T] --------------------------
        u16* T = SMEM;                    // [128 feat][136]
#pragma unroll
        for (int tm = 0; tm < 4; ++tm)
#pragma unroll
            for (int tn = 0; tn < 4; ++tn) {
                const int cl = wn + tn * 16 + l15;            // feature-local
#pragma unroll
                for (int r = 0; r < 4; ++r) {
                    const int rl = wm + tm * 16 + q4 * 4 + r; // t-local
                    T[cl * 136 + rl] = f2b(acc[tm][tn][r]);
                }
            }
        __syncthreads();
        const int b  = m0 >> 8;
        const int t0 = m0 & 255;
        const int fl = tid >> 1;          // feature-local 0..127
        const int hf = tid & 1;           // which 64-t half
        const int fg = n0 + fl;
        const int h  = fg >> 6, d = fg & 63;
        u16* dst = VTd + ((size_t)(b * NHEAD + h) * DHEAD + d) * SEQ + t0 + hf * 64;
        const u16* src = T + fl * 136 + hf * 64;
#pragma unroll
        for (int j = 0; j < 8; ++j)
            *(uint4*)(dst + j * 8) = *(const uint4*)(src + j * 8);
    }
}

// ---- phase 3: causal attention --------------------------------------------
#define PLD 264   // P panel leading dim (u16): mult of 8 (16B align), 2-way banks

template <int CH>
__device__ __forceinline__ void attn_body(
        const u16* __restrict__ Qg, const u16* __restrict__ Kg,
        const u16* __restrict__ VTg, u16* __restrict__ Og, int bh,
        u16* SA, u16* Pbase)
{
    constexpr int NKEY = 64 * (CH + 1);
    constexpr int KT   = NKEY / 16;
    constexpr int NPH  = (NKEY + 127) / 128;

    const int tid  = threadIdx.x;
    const int wv   = tid >> 6;
    const int lane = tid & 63;
    const int l15  = lane & 15;
    const int q4   = lane >> 4;
    const int qrow0 = CH * 64 + wv * 16;
    const int qmax  = qrow0 + 15;
    u16* Pl = Pbase + wv * 16 * PLD;     // per-wave P panel [16 q][PLD]

    short8 aq[2];
#pragma unroll
    for (int ks = 0; ks < 2; ++ks)
        aq[ks] = *(const short8*)(Qg + (size_t)(bh * SEQ + qrow0 + l15) * DHEAD
                                     + ks * 32 + q4 * 8);

    // ---- S = Q K^T * scale, causal --------------------------------------
    u16* Kbuf = SA;                      // [128][72]
    f32x4 s[KT];
#pragma unroll
    for (int ph = 0; ph < NPH; ++ph) {
        const int rows = (NKEY - ph * 128) < 128 ? (NKEY - ph * 128) : 128;
        for (int it = 0; it < rows / 32; ++it) {
            const int r  = it * 32 + (tid >> 3);
            const int d0 = (tid & 7) * 8;
            *(uint4*)(Kbuf + r * 72 + d0) =
                *(const uint4*)(Kg + (size_t)(bh * SEQ + ph * 128 + r) * DHEAD + d0);
        }
        __syncthreads();
#pragma unroll
        for (int t = 0; t < rows / 16; ++t) {
            const int gt = ph * 8 + t;
            if (gt * 16 <= qmax) {
                f32x4 z = {0.f, 0.f, 0.f, 0.f};
#pragma unroll
                for (int ks = 0; ks < 2; ++ks) {
                    short8 bk = *(const short8*)(Kbuf + (t * 16 + l15) * 72
                                                 + ks * 32 + q4 * 8);
                    z = mfma16(aq[ks], bk, z);
                }
                const int kc = gt * 16 + l15;
#pragma unroll
                for (int r = 0; r < 4; ++r) {
                    float v = z[r] * SCALE;
                    if (kc > qrow0 + q4 * 4 + r) v = -1e30f;
                    z[r] = v;
                }
                s[gt] = z;
            } else {
                f32x4 neg = {-1e30f, -1e30f, -1e30f, -1e30f};
                s[gt] = neg;
            }
        }
        __syncthreads();
    }

    // ---- softmax --------------------------------------------------------
    float mx[4], sm[4], rs[4];
#pragma unroll
    for (int r = 0; r < 4; ++r) {
        float m = -1e30f;
#pragma unroll
        for (int t = 0; t < KT; ++t) m = fmaxf(m, s[t][r]);
#pragma unroll
        for (int off = 1; off < 16; off <<= 1)
            m = fmaxf(m, __shfl_xor(m, off, 16));
        mx[r] = m;
        sm[r] = 0.f;
    }
#pragma unroll
    for (int t = 0; t < KT; ++t)
#pragma unroll
        for (int r = 0; r < 4; ++r) {
            float p = __expf(s[t][r] - mx[r]);
            s[t][r] = p;
            sm[r] += p;
        }
#pragma unroll
    for (int r = 0; r < 4; ++r) {
#pragma unroll
        for (int off = 1; off < 16; off <<= 1)
            sm[r] += __shfl_xor(sm[r], off, 16);
        rs[r] = 1.f / sm[r];
    }

    // ---- bulk P write (once; per-wave panel, no cross-wave sync) --------
#pragma unroll
    for (int gt = 0; gt < KT; ++gt)
#pragma unroll
        for (int r = 0; r < 4; ++r)
            Pl[(q4 * 4 + r) * PLD + gt * 16 + l15] = f2b(s[gt][r]);
    // visibility: the __syncthreads after V staging below drains lgkmcnt

    // ---- O = P V (pure ds_read + MFMA) ----------------------------------
    u16* Vt = SA;                        // [64 d][136]
    f32x4 o[4] = {};
#pragma unroll
    for (int ph = 0; ph < NPH; ++ph) {
        const int rows = (NKEY - ph * 128) < 128 ? (NKEY - ph * 128) : 128;
        const int cpr  = rows >> 3;      // uint4 chunks per d-row
#pragma unroll
        for (int it = 0; it < 4; ++it) {
            if (it < cpr / 4) {
                const int flat = it * 256 + tid;
                const int rd = flat / cpr;
                const int kc = (flat - rd * cpr) * 8;
                *(uint4*)(Vt + rd * 136 + kc) =
                    *(const uint4*)(VTg + ((size_t)bh * DHEAD + rd) * SEQ
                                        + ph * 128 + kc);
            }
        }
        __syncthreads();
#pragma unroll
        for (int ks = 0; ks < rows / 32; ++ks) {
            const int gks = ph * 4 + ks;
            if (gks * 32 <= qmax) {
                short8 ap = *(const short8*)(Pl + l15 * PLD + gks * 32 + q4 * 8);
#pragma unroll
                for (int tn = 0; tn < 4; ++tn) {
                    short8 bv = *(const short8*)(Vt + (tn * 16 + l15) * 136
                                                 + ks * 32 + q4 * 8);
                    o[tn] = mfma16(ap, bv, o[tn]);
                }
            }
        }
        __syncthreads();
    }

    // ---- store O -> ws [B,H,T,D], coalesced via LDS ---------------------
    u16* OL = SA;                        // [64 q][64 d], XOR chunk-swz
#pragma unroll
    for (int tn = 0; tn < 4; ++tn) {
        const int col = tn * 16 + l15;
#pragma unroll
        for (int r = 0; r < 4; ++r) {
            const int row = wv * 16 + q4 * 4 + r;
            OL[row * 64 + (((col >> 3) ^ (row & 7)) << 3) + (col & 7)] =
                f2b(o[tn][r] * rs[r]);
        }
    }
    __syncthreads();
    const int seg0 = tid >> 3;           // 0..31
    const int c    = tid & 7;
#pragma unroll
    for (int it = 0; it < 2; ++it) {
        const int row = it * 32 + seg0;  // 0..63
        const int chunk = c ^ (row & 7);
        *(uint4*)(Og + (size_t)(bh * SEQ + CH * 64 + row) * DHEAD + c * 8) =
            *(const uint4*)(OL + row * 64 + chunk * 8);
    }
}

__device__ __forceinline__ void attn_dispatch(
        int ch, int bh,
        const u16* __restrict__ Qg, const u16* __restrict__ Kg,
        const u16* __restrict__ VTg, u16* __restrict__ Og,
        u16* SA, u16* Pbase)
{
    switch (ch) {
        case 0: attn_body<0>(Qg, Kg, VTg, Og, bh, SA, Pbase); break;
        case 1: attn_body<1>(Qg, Kg, VTg, Og, bh, SA, Pbase); break;
        case 2: attn_body<2>(Qg, Kg, VTg, Og, bh, SA, Pbase); break;
        default: attn_body<3>(Qg, Kg, VTg, Og, bh, SA, Pbase); break;
    }
}

// ---- phase 4: output projection out = O @ Wo^T + bo -----------------------
__device__ __forceinline__ void out_body(
        int n0, int m0, u16* SMEM,
        const u16* __restrict__ O, const u16* __restrict__ Wo,
        const float* __restrict__ bias, float* __restrict__ out)
{
    u16* As = SMEM;           // 64 x 64
    u16* Bs = SMEM + 4096;    // 128 x 64

    const int tid  = threadIdx.x;
    const int lane = tid & 63;
    const int wv   = tid >> 6;
    const int l15  = lane & 15;
    const int q4   = lane >> 4;
    const int wm   = (wv >> 1) * 32;
    const int wn   = (wv & 1) * 64;

    f32x4 acc[2][4] = {};

    for (int kk = 0; kk < CDIM; kk += 64) {
        __syncthreads();
#pragma unroll
        for (int ch = 0; ch < 4; ++ch) {
            const int f = (ch * 256 + tid) * 8;
            const int r = f >> 6;
            const int c = (f ^ ((r & 7) << 3)) & 63;
            const int lb = (ch * 256 + wv * 64) * 8;
            gload_lds16(Wo + (size_t)(n0 + r) * CDIM + kk + c, Bs + lb);
            if (ch < 2) {
                const int row = m0 + r;
                const int b = row >> 8, t = row & 255;
                const int k = kk + c;
                const int hh = k >> 6, dd = k & 63;
                gload_lds16(O + (size_t)((b * NHEAD + hh) * SEQ + t) * DHEAD + dd,
                            As + lb);
            }
        }
        __syncthreads();

#pragma unroll
        for (int ks = 0; ks < 2; ++ks) {
            short8 af[2], bf[4];
#pragma unroll
            for (int t = 0; t < 2; ++t) {
                const int ra = wm + t * 16 + l15;
                af[t] = *(const short8*)(As + ra * 64 +
                        ((ks * 32 + q4 * 8) ^ ((ra & 7) << 3)));
            }
#pragma unroll
            for (int t = 0; t < 4; ++t) {
                const int rb = wn + t * 16 + l15;
                bf[t] = *(const short8*)(Bs + rb * 64 +
                        ((ks * 32 + q4 * 8) ^ ((rb & 7) << 3)));
            }
#pragma unroll
            for (int tm = 0; tm < 2; ++tm)
#pragma unroll
                for (int tn = 0; tn < 4; ++tn)
                    acc[tm][tn] = mfma16(af[tm], bf[tn], acc[tm][tn]);
        }
    }

#pragma unroll
    for (int tm = 0; tm < 2; ++tm) {
#pragma unroll
        for (int tn = 0; tn < 4; ++tn) {
            const int col = n0 + wn + tn * 16 + l15;
            const float bb = bias[col];
#pragma unroll
            for (int r = 0; r < 4; ++r) {
                const int row = m0 + wm + tm * 16 + q4 * 4 + r;
                out[(size_t)row * CDIM + col] = acc[tm][tn][r] + bb;  // fp32
            }
        }
    }
}

// ===========================================================================
// Fused cooperative megakernel: one dispatch, grid.sync() between phases.
// LDS: max(qkv 34816 B, attn 18432+33792 B, out 24576 B) = 52224 B.
// ===========================================================================
#define SMEM_U16 26112   // 52224 bytes

__global__ __launch_bounds__(256) void mega(
        const float* __restrict__ x,
        const float* __restrict__ Wk, const float* __restrict__ Wq,
        const float* __restrict__ Wv, const float* __restrict__ Wo,
        const float* __restrict__ bo,
        u16* xb, u16* Wkb, u16* Wqb, u16* Wvb, u16* Wob,
        u16* Kw, u16* Qw, u16* Ow, u16* VTw, float* out)
{
    __shared__ u16 SMEM[SMEM_U16];
    const int gsz = gridDim.x;

    // ---- phase 1: convert ----------------------------------------------
    for (int wb = blockIdx.x; wb < 3360; wb += gsz)
        cvt_body(wb, x, Wk, Wq, Wv, Wo, xb, Wkb, Wqb, Wvb, Wob);

    __threadfence();
    cg::this_grid().sync();

    // ---- phase 2: QKV projection ---------------------------------------
    for (int wb = blockIdx.x; wb < 1152; wb += gsz) {
        const int n0 = (wb % 3) * 128;
        const int m0 = ((wb / 3) & 127) * 128;
        const int z  = wb / 384;
        qkv_body(n0, m0, z, SMEM, xb, Wkb, Wvb, Wqb, Kw, VTw, Qw);
        __syncthreads();
    }

    __threadfence();
    cg::this_grid().sync();

    // ---- phase 3: attention --------------------------------------------
    for (int wb = blockIdx.x; wb < 1536; wb += gsz) {
        attn_dispatch(wb & 3, wb >> 2, Qw, Kw, VTw, Ow,
                      SMEM, SMEM + 9216);
        __syncthreads();
    }

    __threadfence();
    cg::this_grid().sync();

    // ---- phase 4: output projection ------------------------------------
    for (int wb = blockIdx.x; wb < 768; wb += gsz) {
        const int n0 = (wb % 3) * 128;
        const int m0 = (wb / 3) * 64;
        out_body(n0, m0, SMEM, Ow, Wob, bo, out);
        __syncthreads();
    }
}

// ===========================================================================
// Fallback 4-kernel path (identical to R2) in case cooperative launch fails.
// ===========================================================================
__global__ __launch_bounds__(256) void cvt_all_k(
        const float* __restrict__ x,
        const float* __restrict__ Wk, const float* __restrict__ Wq,
        const float* __restrict__ Wv, const float* __restrict__ Wo,
        u16* __restrict__ xb, u16* __restrict__ wkb, u16* __restrict__ wqb,
        u16* __restrict__ wvb, u16* __restrict__ wob)
{
    cvt_body(blockIdx.x, x, Wk, Wq, Wv, Wo, xb, wkb, wqb, wvb, wob);
}

__global__ __launch_bounds__(256) void gemm_qkv_k(
        const u16* __restrict__ X, const u16* __restrict__ Wk,
        const u16* __restrict__ Wv, const u16* __restrict__ Wq,
        u16* __restrict__ Kd, u16* __restrict__ VTd, u16* __restrict__ Qd)
{
    __shared__ u16 SMEM[17408];
    qkv_body(blockIdx.x * 128, blockIdx.y * 128, blockIdx.z, SMEM,
             X, Wk, Wv, Wq, Kd, VTd, Qd);
}

__global__ __launch_bounds__(256) void attn_k(
        const u16* __restrict__ Qg, const u16* __restrict__ Kg,
        const u16* __restrict__ VTg, u16* __restrict__ Og)
{
    __shared__ u16 SA[128 * 72];
    __shared__ u16 Pls[4 * 16 * PLD];
    attn_dispatch(blockIdx.x, blockIdx.y, Qg, Kg, VTg, Og, SA, Pls);
}

__global__ __launch_bounds__(256) void gemm_out_k(
        const u16* __restrict__ O, const u16* __restrict__ Wo,
        const float* __restrict__ bias, float* __restrict__ out)
{
    __shared__ u16 SMEM[64 * 64 + 128 * 64];
    out_body(blockIdx.x * 128, blockIdx.y * 64, SMEM, O, Wo, bias, out);
}

// ===========================================================================
extern "C" void kernel_launch(void* const* d_in, const int* in_sizes, int n_in,
                              void* d_out, int out_size, void* d_ws, size_t ws_size,
                              hipStream_t stream)
{
    const float* x  = (const float*)d_in[0];
    const float* Wk = (const float*)d_in[1];
    const float* Wq = (const float*)d_in[2];
    const float* Wv = (const float*)d_in[3];
    const float* Wo = (const float*)d_in[4];
    const float* bo = (const float*)d_in[5];
    float* out = (float*)d_out;

    // ws layout (u16): xb + 4 weights + K + Q + O  = 51.5 MB
    const size_t SZ = (size_t)NROW * CDIM;   // 6,291,456
    const size_t WZ = (size_t)CDIM * CDIM;   //   147,456
    u16* xb  = (u16*)d_ws;
    u16* Wkb = xb  + SZ;
    u16* Wqb = Wkb + WZ;
    u16* Wvb = Wqb + WZ;
    u16* Wob = Wvb + WZ;
    u16* Kw  = Wob + WZ;
    u16* Qw  = Kw + SZ;
    u16* Ow  = Qw + SZ;
    u16* VTw = (u16*)d_out;   // V^T [B,H,D,T] scratch in d_out (read pre-out-phase)

    // cooperative grid: blocks/CU from occupancy query (graph-capture-safe,
    // pure query), cached. LDS 52.2 KB -> expect 2-3 blocks/CU.
    static int coop_grid = -1;
    if (coop_grid < 0) {
        int nb = 0;
        if (hipOccupancyMaxActiveBlocksPerMultiprocessor(&nb, mega, 256, 0)
                != hipSuccess || nb < 1)
            nb = 1;
        if (nb > 3) nb = 3;
        coop_grid = nb * 256;
    }

    void* args[] = {
        (void*)&x, (void*)&Wk, (void*)&Wq, (void*)&Wv, (void*)&Wo, (void*)&bo,
        (void*)&xb, (void*)&Wkb, (void*)&Wqb, (void*)&Wvb, (void*)&Wob,
        (void*)&Kw, (void*)&Qw, (void*)&Ow, (void*)&VTw, (void*)&out };

    hipError_t e = hipLaunchCooperativeKernel(
        mega, dim3(coop_grid), dim3(256), args, 0, stream);

    if (e != hipSuccess) {
        // fallback: the verified 4-kernel chain
        cvt_all_k<<<dim3(3360), 256, 0, stream>>>(
            x, Wk, Wq, Wv, Wo, xb, Wkb, Wqb, Wvb, Wob);
        dim3 g1(CDIM / 128, NROW / 128, 3);
        gemm_qkv_k<<<g1, 256, 0, stream>>>(xb, Wkb, Wvb, Wqb, Kw, VTw, Qw);
        dim3 g2(4, BATCH * NHEAD);
        attn_k<<<g2, 256, 0, stream>>>(Qw, Kw, VTw, Ow);
        dim3 g3(CDIM / 128, NROW / 64);
        gemm_out_k<<<g3, 256, 0, stream>>>(Ow, Wob, bo, out);
    }
}

// Round 5
// 168.279 us; speedup vs baseline: 2.2080x; 2.2080x over previous
//
#include <hip/hip_runtime.h>
#include <hip/hip_bf16.h>

typedef unsigned short u16;
typedef __attribute__((ext_vector_type(8))) short short8;   // 8 bf16 = 4 VGPRs
typedef __attribute__((ext_vector_type(4))) float f32x4;

#define BATCH 64
#define SEQ   256
#define CDIM  384
#define NHEAD 6
#define DHEAD 64
#define NROW  16384   // BATCH*SEQ

constexpr float SCALE = 0.051031036307982884f;  // 384^-0.5

__device__ __forceinline__ f32x4 mfma16(short8 a, short8 b, f32x4 c) {
    return __builtin_amdgcn_mfma_f32_16x16x32_bf16(a, b, c, 0, 0, 0);
}

__device__ __forceinline__ u16 f2b(float f) {
    __hip_bfloat16 h = __float2bfloat16(f);
    return *reinterpret_cast<u16*>(&h);
}

__device__ __forceinline__ short8 pack8(float4 a, float4 b) {
    short8 r;
    r[0] = (short)f2b(a.x); r[1] = (short)f2b(a.y);
    r[2] = (short)f2b(a.z); r[3] = (short)f2b(a.w);
    r[4] = (short)f2b(b.x); r[5] = (short)f2b(b.y);
    r[6] = (short)f2b(b.z); r[7] = (short)f2b(b.w);
    return r;
}

__device__ __forceinline__ void gload_lds16(const u16* g, u16* l) {
    __builtin_amdgcn_global_load_lds(
        (const __attribute__((address_space(1))) void*)g,
        (__attribute__((address_space(3))) void*)l, 16, 0, 0);
}

// ---------------------------------------------------------------------------
// QKV projection with inline fp32->bf16 conversion: Y = X @ W^T.
// 128x128 tile, BK=64, 4 waves @ 64x64. Staging: load fp32 (2x float4 per
// 8-elem chunk), convert in-register, ds_write short8 DIRECTLY to the
// XOR-swizzled LDS slot (reg-staging => swizzle on the write address).
// grid (3, 128, 3), z:
//   z=0: K -> ws  [B,H,T,D]    z=1: V -> d_out [B,H,D,T] (transposed)
//   z=2: Q -> ws  [B,H,T,D]
// ---------------------------------------------------------------------------
__global__ __launch_bounds__(256) void gemm_qkv(
        const float* __restrict__ X, const float* __restrict__ Wk,
        const float* __restrict__ Wv, const float* __restrict__ Wq,
        u16* __restrict__ Kd, u16* __restrict__ VTd, u16* __restrict__ Qd)
{
    __shared__ u16 SMEM[17408];   // 34 KB: As(8192)+Bs(8192) | epilogue tiles
    u16* As = SMEM;
    u16* Bs = SMEM + 8192;

    const int n0 = blockIdx.x * 128;
    const int m0 = blockIdx.y * 128;
    const int z  = blockIdx.z;
    const float* W = (z == 0) ? Wk : (z == 1 ? Wv : Wq);

    const int tid  = threadIdx.x;
    const int lane = tid & 63;
    const int wv   = tid >> 6;
    const int l15  = lane & 15;
    const int q4   = lane >> 4;
    const int wm   = (wv >> 1) * 64;
    const int wn   = (wv & 1) * 64;

    f32x4 acc[4][4] = {};

    for (int kk = 0; kk < CDIM; kk += 64) {
        __syncthreads();   // previous iteration's LDS readers done
#pragma unroll
        for (int ch = 0; ch < 4; ++ch) {
            const int f = (ch * 256 + tid) * 8;   // linear tile elem index
            const int r = f >> 6;                 // tile row 0..127
            const int c = f & 63;                 // col chunk base (mult of 8)
            const size_t gx = (size_t)(m0 + r) * CDIM + kk + c;
            const size_t gw = (size_t)(n0 + r) * CDIM + kk + c;
            const float4 xa = *(const float4*)(X + gx);
            const float4 xb = *(const float4*)(X + gx + 4);
            const float4 wa = *(const float4*)(W + gw);
            const float4 wb = *(const float4*)(W + gw + 4);
            const int off = r * 64 + (c ^ ((r & 7) << 3));  // swizzled slot
            *(short8*)(As + off) = pack8(xa, xb);
            *(short8*)(Bs + off) = pack8(wa, wb);
        }
        __syncthreads();   // ds_writes visible (barrier drains lgkmcnt)

#pragma unroll
        for (int ks = 0; ks < 2; ++ks) {
            short8 af[4], bf[4];
#pragma unroll
            for (int t = 0; t < 4; ++t) {
                const int ra = wm + t * 16 + l15;
                const int rb = wn + t * 16 + l15;
                af[t] = *(const short8*)(As + ra * 64 +
                        ((ks * 32 + q4 * 8) ^ ((ra & 7) << 3)));
                bf[t] = *(const short8*)(Bs + rb * 64 +
                        ((ks * 32 + q4 * 8) ^ ((rb & 7) << 3)));
            }
#pragma unroll
            for (int tm = 0; tm < 4; ++tm)
#pragma unroll
                for (int tn = 0; tn < 4; ++tn)
                    acc[tm][tn] = mfma16(af[tm], bf[tn], acc[tm][tn]);
        }
    }
    __syncthreads();   // all waves done with As/Bs; SMEM free for epilogue

    if (z != 1) {
        // ---- coalesced epilogue to [B,H,T,D] via LDS --------------------
        u16* D = (z == 0) ? Kd : Qd;
        u16* T = SMEM;                    // [128 t][128 col], XOR chunk-swz
#pragma unroll
        for (int tm = 0; tm < 4; ++tm)
#pragma unroll
            for (int tn = 0; tn < 4; ++tn) {
                const int cl = wn + tn * 16 + l15;
#pragma unroll
                for (int r = 0; r < 4; ++r) {
                    const int row = wm + tm * 16 + q4 * 4 + r;
                    T[row * 128 + (((cl >> 3) ^ (row & 7)) << 3) + (cl & 7)] =
                        f2b(acc[tm][tn][r]);
                }
            }
        __syncthreads();
        const int seg0 = tid >> 3;        // 0..31
        const int c    = tid & 7;         // 16B chunk within 64-d segment
#pragma unroll
        for (int it = 0; it < 8; ++it) {
            const int S   = it * 32 + seg0;   // 0..255: (row, head-half)
            const int row = S >> 1;
            const int hf  = S & 1;
            const int rowg = m0 + row;
            const int b  = rowg >> 8, tt = rowg & 255;
            const int h  = (n0 + hf * 64) >> 6;
            const int chunk = (hf * 8 + c) ^ (row & 7);
            *(uint4*)(D + (size_t)((b * NHEAD + h) * SEQ + tt) * DHEAD + c * 8) =
                *(const uint4*)(T + row * 128 + chunk * 8);
        }
    } else {
        // ---- transpose epilogue: V^T [B,H,D,T] --------------------------
        u16* T = SMEM;                    // [128 feat][136]
#pragma unroll
        for (int tm = 0; tm < 4; ++tm)
#pragma unroll
            for (int tn = 0; tn < 4; ++tn) {
                const int cl = wn + tn * 16 + l15;            // feature-local
#pragma unroll
                for (int r = 0; r < 4; ++r) {
                    const int rl = wm + tm * 16 + q4 * 4 + r; // t-local
                    T[cl * 136 + rl] = f2b(acc[tm][tn][r]);
                }
            }
        __syncthreads();
        const int b  = m0 >> 8;
        const int t0 = m0 & 255;
        const int fl = tid >> 1;          // feature-local 0..127
        const int hf = tid & 1;           // which 64-t half
        const int fg = n0 + fl;
        const int h  = fg >> 6, d = fg & 63;
        u16* dst = VTd + ((size_t)(b * NHEAD + h) * DHEAD + d) * SEQ + t0 + hf * 64;
        const u16* src = T + fl * 136 + hf * 64;
#pragma unroll
        for (int j = 0; j < 8; ++j)
            *(uint4*)(dst + j * 8) = *(const uint4*)(src + j * 8);
    }
}

// ---------------------------------------------------------------------------
// Attention: block = (chunk CH, bh). 64 query rows, causal keys [0,64(CH+1)).
// Identical compute to R2. O written row-major [NROW][CDIM] bf16 so the
// output-projection kernel can stage it with plain linear global_load_lds.
// ---------------------------------------------------------------------------
#define PLD 264   // P panel leading dim (u16): mult of 8 (16B align), 2-way banks

template <int CH>
__device__ __forceinline__ void attn_body(
        const u16* __restrict__ Qg, const u16* __restrict__ Kg,
        const u16* __restrict__ VTg, u16* __restrict__ Og, int bh,
        u16* SA, u16* Pbase)
{
    constexpr int NKEY = 64 * (CH + 1);
    constexpr int KT   = NKEY / 16;
    constexpr int NPH  = (NKEY + 127) / 128;

    const int tid  = threadIdx.x;
    const int wv   = tid >> 6;
    const int lane = tid & 63;
    const int l15  = lane & 15;
    const int q4   = lane >> 4;
    const int qrow0 = CH * 64 + wv * 16;
    const int qmax  = qrow0 + 15;
    u16* Pl = Pbase + wv * 16 * PLD;     // per-wave P panel [16 q][PLD]

    short8 aq[2];
#pragma unroll
    for (int ks = 0; ks < 2; ++ks)
        aq[ks] = *(const short8*)(Qg + (size_t)(bh * SEQ + qrow0 + l15) * DHEAD
                                     + ks * 32 + q4 * 8);

    // ---- S = Q K^T * scale, causal --------------------------------------
    u16* Kbuf = SA;                      // [128][72]
    f32x4 s[KT];
#pragma unroll
    for (int ph = 0; ph < NPH; ++ph) {
        const int rows = (NKEY - ph * 128) < 128 ? (NKEY - ph * 128) : 128;
        for (int it = 0; it < rows / 32; ++it) {
            const int r  = it * 32 + (tid >> 3);
            const int d0 = (tid & 7) * 8;
            *(uint4*)(Kbuf + r * 72 + d0) =
                *(const uint4*)(Kg + (size_t)(bh * SEQ + ph * 128 + r) * DHEAD + d0);
        }
        __syncthreads();
#pragma unroll
        for (int t = 0; t < rows / 16; ++t) {
            const int gt = ph * 8 + t;
            if (gt * 16 <= qmax) {
                f32x4 z = {0.f, 0.f, 0.f, 0.f};
#pragma unroll
                for (int ks = 0; ks < 2; ++ks) {
                    short8 bk = *(const short8*)(Kbuf + (t * 16 + l15) * 72
                                                 + ks * 32 + q4 * 8);
                    z = mfma16(aq[ks], bk, z);
                }
                const int kc = gt * 16 + l15;
#pragma unroll
                for (int r = 0; r < 4; ++r) {
                    float v = z[r] * SCALE;
                    if (kc > qrow0 + q4 * 4 + r) v = -1e30f;
                    z[r] = v;
                }
                s[gt] = z;
            } else {
                f32x4 neg = {-1e30f, -1e30f, -1e30f, -1e30f};
                s[gt] = neg;
            }
        }
        __syncthreads();
    }

    // ---- softmax --------------------------------------------------------
    float mx[4], sm[4], rs[4];
#pragma unroll
    for (int r = 0; r < 4; ++r) {
        float m = -1e30f;
#pragma unroll
        for (int t = 0; t < KT; ++t) m = fmaxf(m, s[t][r]);
#pragma unroll
        for (int off = 1; off < 16; off <<= 1)
            m = fmaxf(m, __shfl_xor(m, off, 16));
        mx[r] = m;
        sm[r] = 0.f;
    }
#pragma unroll
    for (int t = 0; t < KT; ++t)
#pragma unroll
        for (int r = 0; r < 4; ++r) {
            float p = __expf(s[t][r] - mx[r]);
            s[t][r] = p;
            sm[r] += p;
        }
#pragma unroll
    for (int r = 0; r < 4; ++r) {
#pragma unroll
        for (int off = 1; off < 16; off <<= 1)
            sm[r] += __shfl_xor(sm[r], off, 16);
        rs[r] = 1.f / sm[r];
    }

    // ---- bulk P write (once; per-wave panel, no cross-wave sync) --------
#pragma unroll
    for (int gt = 0; gt < KT; ++gt)
#pragma unroll
        for (int r = 0; r < 4; ++r)
            Pl[(q4 * 4 + r) * PLD + gt * 16 + l15] = f2b(s[gt][r]);
    // visibility: the __syncthreads after V staging below drains lgkmcnt

    // ---- O = P V (pure ds_read + MFMA) ----------------------------------
    u16* Vt = SA;                        // [64 d][136]
    f32x4 o[4] = {};
#pragma unroll
    for (int ph = 0; ph < NPH; ++ph) {
        const int rows = (NKEY - ph * 128) < 128 ? (NKEY - ph * 128) : 128;
        const int cpr  = rows >> 3;      // uint4 chunks per d-row
#pragma unroll
        for (int it = 0; it < 4; ++it) {
            if (it < cpr / 4) {
                const int flat = it * 256 + tid;
                const int rd = flat / cpr;
                const int kc = (flat - rd * cpr) * 8;
                *(uint4*)(Vt + rd * 136 + kc) =
                    *(const uint4*)(VTg + ((size_t)bh * DHEAD + rd) * SEQ
                                        + ph * 128 + kc);
            }
        }
        __syncthreads();
#pragma unroll
        for (int ks = 0; ks < rows / 32; ++ks) {
            const int gks = ph * 4 + ks;
            if (gks * 32 <= qmax) {
                short8 ap = *(const short8*)(Pl + l15 * PLD + gks * 32 + q4 * 8);
#pragma unroll
                for (int tn = 0; tn < 4; ++tn) {
                    short8 bv = *(const short8*)(Vt + (tn * 16 + l15) * 136
                                                 + ks * 32 + q4 * 8);
                    o[tn] = mfma16(ap, bv, o[tn]);
                }
            }
        }
        __syncthreads();
    }

    // ---- store O -> ws [NROW][CDIM] bf16, coalesced via LDS -------------
    u16* OL = SA;                        // [64 q][64 d], XOR chunk-swz
#pragma unroll
    for (int tn = 0; tn < 4; ++tn) {
        const int col = tn * 16 + l15;
#pragma unroll
        for (int r = 0; r < 4; ++r) {
            const int row = wv * 16 + q4 * 4 + r;
            OL[row * 64 + (((col >> 3) ^ (row & 7)) << 3) + (col & 7)] =
                f2b(o[tn][r] * rs[r]);
        }
    }
    __syncthreads();
    const int b  = bh / NHEAD;
    const int h  = bh - b * NHEAD;
    const int seg0 = tid >> 3;           // 0..31
    const int c    = tid & 7;
#pragma unroll
    for (int it = 0; it < 2; ++it) {
        const int row = it * 32 + seg0;  // 0..63
        const int chunk = c ^ (row & 7);
        *(uint4*)(Og + (size_t)(b * SEQ + CH * 64 + row) * CDIM
                     + h * DHEAD + c * 8) =
            *(const uint4*)(OL + row * 64 + chunk * 8);
    }
}

__global__ __launch_bounds__(256) void attn_kernel(
        const u16* __restrict__ Qg, const u16* __restrict__ Kg,
        const u16* __restrict__ VTg, u16* __restrict__ Og)
{
    __shared__ u16 SA[128 * 72];        // 18 KB, phase-aliased (Kbuf/Vt/OL)
    __shared__ u16 Pls[4 * 16 * PLD];   // 33 KB, per-wave P panels
    const int bh = blockIdx.y;
    switch (blockIdx.x) {
        case 0: attn_body<0>(Qg, Kg, VTg, Og, bh, SA, Pls); break;
        case 1: attn_body<1>(Qg, Kg, VTg, Og, bh, SA, Pls); break;
        case 2: attn_body<2>(Qg, Kg, VTg, Og, bh, SA, Pls); break;
        default: attn_body<3>(Qg, Kg, VTg, Og, bh, SA, Pls); break;
    }
}

// ---------------------------------------------------------------------------
// Output projection with inline Wo conversion: out = O @ Wo^T + bo.
// O bf16 [NROW][CDIM] (linear global_load_lds staging, inverse-swizzled src),
// Wo fp32 (reg-staged fp32->bf16 to swizzled LDS), bo fp32.
// 64x128 tile (grid 3x256 = 768 blocks), BK=64. Writes fp32 [16384x384].
// ---------------------------------------------------------------------------
__global__ __launch_bounds__(256) void gemm_out(
        const u16* __restrict__ O, const float* __restrict__ Wo,
        const float* __restrict__ bias, float* __restrict__ out)
{
    __shared__ u16 As[64 * 64];    //  8 KB
    __shared__ u16 Bs[128 * 64];   // 16 KB

    const int n0 = blockIdx.x * 128;
    const int m0 = blockIdx.y * 64;

    const int tid  = threadIdx.x;
    const int lane = tid & 63;
    const int wv   = tid >> 6;
    const int l15  = lane & 15;
    const int q4   = lane >> 4;
    const int wm   = (wv >> 1) * 32;
    const int wn   = (wv & 1) * 64;

    f32x4 acc[2][4] = {};

    for (int kk = 0; kk < CDIM; kk += 64) {
        __syncthreads();
        // ---- As: O rows via async global_load_lds (linear dest,
        //          inverse-swizzled source column) ------------------------
#pragma unroll
        for (int ch = 0; ch < 2; ++ch) {
            const int f = (ch * 256 + tid) * 8;
            const int r = f >> 6;
            const int c = (f ^ ((r & 7) << 3)) & 63;
            const int lb = (ch * 256 + wv * 64) * 8;
            gload_lds16(O + (size_t)(m0 + r) * CDIM + kk + c, As + lb);
        }
        // ---- Bs: Wo fp32 -> bf16 reg-staged to swizzled slots -----------
#pragma unroll
        for (int ch = 0; ch < 4; ++ch) {
            const int f = (ch * 256 + tid) * 8;
            const int r = f >> 6;
            const int c = f & 63;
            const size_t gw = (size_t)(n0 + r) * CDIM + kk + c;
            const float4 wa = *(const float4*)(Wo + gw);
            const float4 wb = *(const float4*)(Wo + gw + 4);
            *(short8*)(Bs + r * 64 + (c ^ ((r & 7) << 3))) = pack8(wa, wb);
        }
        __syncthreads();   // drains vmcnt (As) and lgkmcnt (Bs)

#pragma unroll
        for (int ks = 0; ks < 2; ++ks) {
            short8 af[2], bf[4];
#pragma unroll
            for (int t = 0; t < 2; ++t) {
                const int ra = wm + t * 16 + l15;
                af[t] = *(const short8*)(As + ra * 64 +
                        ((ks * 32 + q4 * 8) ^ ((ra & 7) << 3)));
            }
#pragma unroll
            for (int t = 0; t < 4; ++t) {
                const int rb = wn + t * 16 + l15;
                bf[t] = *(const short8*)(Bs + rb * 64 +
                        ((ks * 32 + q4 * 8) ^ ((rb & 7) << 3)));
            }
#pragma unroll
            for (int tm = 0; tm < 2; ++tm)
#pragma unroll
                for (int tn = 0; tn < 4; ++tn)
                    acc[tm][tn] = mfma16(af[tm], bf[tn], acc[tm][tn]);
        }
    }

#pragma unroll
    for (int tm = 0; tm < 2; ++tm) {
#pragma unroll
        for (int tn = 0; tn < 4; ++tn) {
            const int col = n0 + wn + tn * 16 + l15;
            const float bb = bias[col];
#pragma unroll
            for (int r = 0; r < 4; ++r) {
                const int row = m0 + wm + tm * 16 + q4 * 4 + r;
                out[(size_t)row * CDIM + col] = acc[tm][tn][r] + bb;  // fp32
            }
        }
    }
}

extern "C" void kernel_launch(void* const* d_in, const int* in_sizes, int n_in,
                              void* d_out, int out_size, void* d_ws, size_t ws_size,
                              hipStream_t stream)
{
    const float* x  = (const float*)d_in[0];
    const float* Wk = (const float*)d_in[1];
    const float* Wq = (const float*)d_in[2];
    const float* Wv = (const float*)d_in[3];
    const float* Wo = (const float*)d_in[4];
    const float* bo = (const float*)d_in[5];
    float* out = (float*)d_out;

    // ws layout (u16): K + Q + O = 37.7 MB (conversion now inline in GEMMs)
    const size_t SZ = (size_t)NROW * CDIM;   // 6,291,456
    u16* Kw  = (u16*)d_ws;
    u16* Qw  = Kw + SZ;
    u16* Ow  = Qw + SZ;
    u16* VTw = (u16*)d_out;   // V^T [B,H,D,T] scratch in d_out (dead before out-proj writes)

    dim3 g1(CDIM / 128, NROW / 128, 3);
    gemm_qkv<<<g1, 256, 0, stream>>>(x, Wk, Wv, Wq, Kw, VTw, Qw);

    dim3 g2(4, BATCH * NHEAD);
    attn_kernel<<<g2, 256, 0, stream>>>(Qw, Kw, VTw, Ow);

    dim3 g3(CDIM / 128, NROW / 64);
    gemm_out<<<g3, 256, 0, stream>>>(Ow, Wo, bo, out);
}

// Round 7
// 152.296 us; speedup vs baseline: 2.4398x; 1.1049x over previous
//
#include <hip/hip_runtime.h>
#include <hip/hip_bf16.h>

typedef unsigned short u16;
typedef __attribute__((ext_vector_type(8))) short short8;   // 8 bf16 = 4 VGPRs
typedef __attribute__((ext_vector_type(4))) float f32x4;

#define BATCH 64
#define SEQ   256
#define CDIM  384
#define NHEAD 6
#define DHEAD 64
#define NROW  16384   // BATCH*SEQ

constexpr float SCALE = 0.051031036307982884f;  // 384^-0.5

__device__ __forceinline__ f32x4 mfma16(short8 a, short8 b, f32x4 c) {
    return __builtin_amdgcn_mfma_f32_16x16x32_bf16(a, b, c, 0, 0, 0);
}

__device__ __forceinline__ u16 f2b(float f) {
    __hip_bfloat16 h = __float2bfloat16(f);
    return *reinterpret_cast<u16*>(&h);
}

__device__ __forceinline__ void gload_lds16(const u16* g, u16* l) {
    __builtin_amdgcn_global_load_lds(
        (const __attribute__((address_space(1))) void*)g,
        (__attribute__((address_space(3))) void*)l, 16, 0, 0);
}

// ---------------------------------------------------------------------------
// fp32 -> bf16 conversion for x AND the 4 weights, one launch.
// blocks [0,3072): x (6291456 elems); [3072,3360): weights, 72 blocks each.
// ---------------------------------------------------------------------------
__global__ __launch_bounds__(256) void cvt_all(
        const float* __restrict__ x,
        const float* __restrict__ Wk, const float* __restrict__ Wq,
        const float* __restrict__ Wv, const float* __restrict__ Wo,
        u16* __restrict__ xb,
        u16* __restrict__ wkb, u16* __restrict__ wqb,
        u16* __restrict__ wvb, u16* __restrict__ wob)
{
    int blk = blockIdx.x;
    const float* s;
    u16* d;
    if (blk < 3072) {
        s = x; d = xb;
    } else {
        const int w = blk - 3072;
        const int z = w / 72;           // 0..3
        blk = w - z * 72;
        s = (z == 0) ? Wk : (z == 1) ? Wq : (z == 2) ? Wv : Wo;
        d = (z == 0) ? wkb : (z == 1) ? wqb : (z == 2) ? wvb : wob;
    }
    const int i = (blk * 256 + (int)threadIdx.x) * 8;
    const float4 a = *(const float4*)(s + i);
    const float4 b = *(const float4*)(s + i + 4);
    short8 r;
    r[0] = (short)f2b(a.x); r[1] = (short)f2b(a.y);
    r[2] = (short)f2b(a.z); r[3] = (short)f2b(a.w);
    r[4] = (short)f2b(b.x); r[5] = (short)f2b(b.y);
    r[6] = (short)f2b(b.z); r[7] = (short)f2b(b.w);
    *(short8*)(d + i) = r;
}

// ---------------------------------------------------------------------------
// QKV projection (all-bf16): Y = X @ W^T. 128x128 tile, BK=64, 4 waves @
// 64x64. global_load_lds(16B) staging into XOR-swizzled [128][64] tiles.
// XCD-aware block swizzle: the 9 blocks (3 n0 x 3 z) sharing one X m-panel
// are mapped to the SAME XCD (1152 blocks = 8 XCD x 16 panels x 9 sharers,
// bijective), so the 98 KB bf16 X panel is fetched into one L2 once and
// L2-hits for the other 8 uses.
//   z=0: K -> ws  [B,H,T,D]    z=1: V -> d_out [B,H,D,T] (transposed)
//   z=2: Q -> ws  [B,H,T,D]
// ---------------------------------------------------------------------------
__global__ __launch_bounds__(256) void gemm_qkv(
        const u16* __restrict__ X, const u16* __restrict__ Wk,
        const u16* __restrict__ Wv, const u16* __restrict__ Wq,
        u16* __restrict__ Kd, u16* __restrict__ VTd, u16* __restrict__ Qd)
{
    __shared__ u16 SMEM[17408];   // 34 KB: As(8192)+Bs(8192) | epilogue tiles
    u16* As = SMEM;
    u16* Bs = SMEM + 8192;

    // ---- XCD-locality decode (blocks dispatched round-robin over 8 XCDs) --
    const int bid   = blockIdx.x;        // 0..1151
    const int xcd   = bid & 7;
    const int i     = bid >> 3;          // 0..143
    const int igrp  = i / 9;             // 0..15  (panel within this XCD)
    const int j     = i - igrp * 9;      // 0..8   (sharer: n0 x z)
    const int panel = xcd * 16 + igrp;   // 0..127 (m-panel)
    const int m0    = panel * 128;
    const int n0    = (j % 3) * 128;
    const int z     = j / 3;
    const u16* W = (z == 0) ? Wk : (z == 1 ? Wv : Wq);

    const int tid  = threadIdx.x;
    const int lane = tid & 63;
    const int wv   = tid >> 6;
    const int l15  = lane & 15;
    const int q4   = lane >> 4;
    const int wm   = (wv >> 1) * 64;
    const int wn   = (wv & 1) * 64;

    f32x4 acc[4][4] = {};

    for (int kk = 0; kk < CDIM; kk += 64) {
        __syncthreads();   // previous iteration's LDS readers done
#pragma unroll
        for (int ch = 0; ch < 4; ++ch) {
            const int f = (ch * 256 + tid) * 8;   // linear LDS elem index
            const int r = f >> 6;
            // inverse-swizzled global column so value lands at swizzled slot
            const int c = (f ^ ((r & 7) << 3)) & 63;
            const int lb = (ch * 256 + wv * 64) * 8;   // wave-uniform LDS base
            gload_lds16(X + (size_t)(m0 + r) * CDIM + kk + c, As + lb);
            gload_lds16(W + (size_t)(n0 + r) * CDIM + kk + c, Bs + lb);
        }
        __syncthreads();   // staging complete (vmcnt drained by barrier)

#pragma unroll
        for (int ks = 0; ks < 2; ++ks) {
            short8 af[4], bf[4];
#pragma unroll
            for (int t = 0; t < 4; ++t) {
                const int ra = wm + t * 16 + l15;
                const int rb = wn + t * 16 + l15;
                af[t] = *(const short8*)(As + ra * 64 +
                        ((ks * 32 + q4 * 8) ^ ((ra & 7) << 3)));
                bf[t] = *(const short8*)(Bs + rb * 64 +
                        ((ks * 32 + q4 * 8) ^ ((rb & 7) << 3)));
            }
#pragma unroll
            for (int tm = 0; tm < 4; ++tm)
#pragma unroll
                for (int tn = 0; tn < 4; ++tn)
                    acc[tm][tn] = mfma16(af[tm], bf[tn], acc[tm][tn]);
        }
    }
    __syncthreads();   // all waves done with As/Bs; SMEM free for epilogue

    if (z != 1) {
        // ---- coalesced epilogue to [B,H,T,D] via LDS --------------------
        u16* D = (z == 0) ? Kd : Qd;
        u16* T = SMEM;                    // [128 t][128 col], XOR chunk-swz
#pragma unroll
        for (int tm = 0; tm < 4; ++tm)
#pragma unroll
            for (int tn = 0; tn < 4; ++tn) {
                const int cl = wn + tn * 16 + l15;
#pragma unroll
                for (int r = 0; r < 4; ++r) {
                    const int row = wm + tm * 16 + q4 * 4 + r;
                    T[row * 128 + (((cl >> 3) ^ (row & 7)) << 3) + (cl & 7)] =
                        f2b(acc[tm][tn][r]);
                }
            }
        __syncthreads();
        const int seg0 = tid >> 3;        // 0..31
        const int c    = tid & 7;         // 16B chunk within 64-d segment
#pragma unroll
        for (int it = 0; it < 8; ++it) {
            const int S   = it * 32 + seg0;   // 0..255: (row, head-half)
            const int row = S >> 1;
            const int hf  = S & 1;
            const int rowg = m0 + row;
            const int b  = rowg >> 8, tt = rowg & 255;
            const int h  = (n0 + hf * 64) >> 6;
            const int chunk = (hf * 8 + c) ^ (row & 7);
            *(uint4*)(D + (size_t)((b * NHEAD + h) * SEQ + tt) * DHEAD + c * 8) =
                *(const uint4*)(T + row * 128 + chunk * 8);
        }
    } else {
        // ---- transpose epilogue: V^T [B,H,D,T] --------------------------
        u16* T = SMEM;                    // [128 feat][136]
#pragma unroll
        for (int tm = 0; tm < 4; ++tm)
#pragma unroll
            for (int tn = 0; tn < 4; ++tn) {
                const int cl = wn + tn * 16 + l15;            // feature-local
#pragma unroll
                for (int r = 0; r < 4; ++r) {
                    const int rl = wm + tm * 16 + q4 * 4 + r; // t-local
                    T[cl * 136 + rl] = f2b(acc[tm][tn][r]);
                }
            }
        __syncthreads();
        const int b  = m0 >> 8;
        const int t0 = m0 & 255;
        const int fl = tid >> 1;          // feature-local 0..127
        const int hf = tid & 1;           // which 64-t half
        const int fg = n0 + fl;
        const int h  = fg >> 6, d = fg & 63;
        u16* dst = VTd + ((size_t)(b * NHEAD + h) * DHEAD + d) * SEQ + t0 + hf * 64;
        const u16* src = T + fl * 136 + hf * 64;
#pragma unroll
        for (int j2 = 0; j2 < 8; ++j2)
            *(uint4*)(dst + j2 * 8) = *(const uint4*)(src + j2 * 8);
    }
}

// ---------------------------------------------------------------------------
// Attention: block = (chunk CH, bh). 64 query rows, causal keys [0,64(CH+1)).
// O written row-major [NROW][CDIM] bf16 (coalesced uint4 via LDS).
// ---------------------------------------------------------------------------
#define PLD 264   // P panel leading dim (u16): mult of 8 (16B align), 2-way banks

template <int CH>
__device__ __forceinline__ void attn_body(
        const u16* __restrict__ Qg, const u16* __restrict__ Kg,
        const u16* __restrict__ VTg, u16* __restrict__ Og, int bh,
        u16* SA, u16* Pbase)
{
    constexpr int NKEY = 64 * (CH + 1);
    constexpr int KT   = NKEY / 16;
    constexpr int NPH  = (NKEY + 127) / 128;

    const int tid  = threadIdx.x;
    const int wv   = tid >> 6;
    const int lane = tid & 63;
    const int l15  = lane & 15;
    const int q4   = lane >> 4;
    const int qrow0 = CH * 64 + wv * 16;
    const int qmax  = qrow0 + 15;
    u16* Pl = Pbase + wv * 16 * PLD;     // per-wave P panel [16 q][PLD]

    short8 aq[2];
#pragma unroll
    for (int ks = 0; ks < 2; ++ks)
        aq[ks] = *(const short8*)(Qg + (size_t)(bh * SEQ + qrow0 + l15) * DHEAD
                                     + ks * 32 + q4 * 8);

    // ---- S = Q K^T * scale, causal --------------------------------------
    u16* Kbuf = SA;                      // [128][72]
    f32x4 s[KT];
#pragma unroll
    for (int ph = 0; ph < NPH; ++ph) {
        const int rows = (NKEY - ph * 128) < 128 ? (NKEY - ph * 128) : 128;
        for (int it = 0; it < rows / 32; ++it) {
            const int r  = it * 32 + (tid >> 3);
            const int d0 = (tid & 7) * 8;
            *(uint4*)(Kbuf + r * 72 + d0) =
                *(const uint4*)(Kg + (size_t)(bh * SEQ + ph * 128 + r) * DHEAD + d0);
        }
        __syncthreads();
#pragma unroll
        for (int t = 0; t < rows / 16; ++t) {
            const int gt = ph * 8 + t;
            if (gt * 16 <= qmax) {
                f32x4 z = {0.f, 0.f, 0.f, 0.f};
#pragma unroll
                for (int ks = 0; ks < 2; ++ks) {
                    short8 bk = *(const short8*)(Kbuf + (t * 16 + l15) * 72
                                                 + ks * 32 + q4 * 8);
                    z = mfma16(aq[ks], bk, z);
                }
                const int kc = gt * 16 + l15;
#pragma unroll
                for (int r = 0; r < 4; ++r) {
                    float v = z[r] * SCALE;
                    if (kc > qrow0 + q4 * 4 + r) v = -1e30f;
                    z[r] = v;
                }
                s[gt] = z;
            } else {
                f32x4 neg = {-1e30f, -1e30f, -1e30f, -1e30f};
                s[gt] = neg;
            }
        }
        __syncthreads();
    }

    // ---- softmax --------------------------------------------------------
    float mx[4], sm[4], rs[4];
#pragma unroll
    for (int r = 0; r < 4; ++r) {
        float m = -1e30f;
#pragma unroll
        for (int t = 0; t < KT; ++t) m = fmaxf(m, s[t][r]);
#pragma unroll
        for (int off = 1; off < 16; off <<= 1)
            m = fmaxf(m, __shfl_xor(m, off, 16));
        mx[r] = m;
        sm[r] = 0.f;
    }
#pragma unroll
    for (int t = 0; t < KT; ++t)
#pragma unroll
        for (int r = 0; r < 4; ++r) {
            float p = __expf(s[t][r] - mx[r]);
            s[t][r] = p;
            sm[r] += p;
        }
#pragma unroll
    for (int r = 0; r < 4; ++r) {
#pragma unroll
        for (int off = 1; off < 16; off <<= 1)
            sm[r] += __shfl_xor(sm[r], off, 16);
        rs[r] = 1.f / sm[r];
    }

    // ---- bulk P write (once; per-wave panel, no cross-wave sync) --------
#pragma unroll
    for (int gt = 0; gt < KT; ++gt)
#pragma unroll
        for (int r = 0; r < 4; ++r)
            Pl[(q4 * 4 + r) * PLD + gt * 16 + l15] = f2b(s[gt][r]);
    // visibility: the __syncthreads after V staging below drains lgkmcnt

    // ---- O = P V (pure ds_read + MFMA) ----------------------------------
    u16* Vt = SA;                        // [64 d][136]
    f32x4 o[4] = {};
#pragma unroll
    for (int ph = 0; ph < NPH; ++ph) {
        const int rows = (NKEY - ph * 128) < 128 ? (NKEY - ph * 128) : 128;
        const int cpr  = rows >> 3;      // uint4 chunks per d-row
#pragma unroll
        for (int it = 0; it < 4; ++it) {
            if (it < cpr / 4) {
                const int flat = it * 256 + tid;
                const int rd = flat / cpr;
                const int kc = (flat - rd * cpr) * 8;
                *(uint4*)(Vt + rd * 136 + kc) =
                    *(const uint4*)(VTg + ((size_t)bh * DHEAD + rd) * SEQ
                                        + ph * 128 + kc);
            }
        }
        __syncthreads();
#pragma unroll
        for (int ks = 0; ks < rows / 32; ++ks) {
            const int gks = ph * 4 + ks;
            if (gks * 32 <= qmax) {
                short8 ap = *(const short8*)(Pl + l15 * PLD + gks * 32 + q4 * 8);
#pragma unroll
                for (int tn = 0; tn < 4; ++tn) {
                    short8 bv = *(const short8*)(Vt + (tn * 16 + l15) * 136
                                                 + ks * 32 + q4 * 8);
                    o[tn] = mfma16(ap, bv, o[tn]);
                }
            }
        }
        __syncthreads();
    }

    // ---- store O -> ws [NROW][CDIM] bf16, coalesced via LDS -------------
    u16* OL = SA;                        // [64 q][64 d], XOR chunk-swz
#pragma unroll
    for (int tn = 0; tn < 4; ++tn) {
        const int col = tn * 16 + l15;
#pragma unroll
        for (int r = 0; r < 4; ++r) {
            const int row = wv * 16 + q4 * 4 + r;
            OL[row * 64 + (((col >> 3) ^ (row & 7)) << 3) + (col & 7)] =
                f2b(o[tn][r] * rs[r]);
        }
    }
    __syncthreads();
    const int b  = bh / NHEAD;
    const int h  = bh - b * NHEAD;
    const int seg0 = tid >> 3;           // 0..31
    const int c    = tid & 7;
#pragma unroll
    for (int it = 0; it < 2; ++it) {
        const int row = it * 32 + seg0;  // 0..63
        const int chunk = c ^ (row & 7);
        *(uint4*)(Og + (size_t)(b * SEQ + CH * 64 + row) * CDIM
                     + h * DHEAD + c * 8) =
            *(const uint4*)(OL + row * 64 + chunk * 8);
    }
}

__global__ __launch_bounds__(256) void attn_kernel(
        const u16* __restrict__ Qg, const u16* __restrict__ Kg,
        const u16* __restrict__ VTg, u16* __restrict__ Og)
{
    __shared__ u16 SA[128 * 72];        // 18 KB, phase-aliased (Kbuf/Vt/OL)
    __shared__ u16 Pls[4 * 16 * PLD];   // 33 KB, per-wave P panels
    const int bh = blockIdx.y;
    switch (blockIdx.x) {
        case 0: attn_body<0>(Qg, Kg, VTg, Og, bh, SA, Pls); break;
        case 1: attn_body<1>(Qg, Kg, VTg, Og, bh, SA, Pls); break;
        case 2: attn_body<2>(Qg, Kg, VTg, Og, bh, SA, Pls); break;
        default: attn_body<3>(Qg, Kg, VTg, Og, bh, SA, Pls); break;
    }
}

// ---------------------------------------------------------------------------
// Output projection (bf16 inputs): out = O @ Wo^T + bo. O bf16 [NROW][CDIM]
// row-major (linear global_load_lds staging), Wo bf16, bo fp32.
// 64x128 tile (grid 3x256 = 768 blocks), BK=64, XOR-swizzled LDS.
// Writes fp32 row-major [16384x384].
// ---------------------------------------------------------------------------
__global__ __launch_bounds__(256) void gemm_out(
        const u16* __restrict__ O, const u16* __restrict__ Wo,
        const float* __restrict__ bias, float* __restrict__ out)
{
    __shared__ u16 As[64 * 64];    //  8 KB
    __shared__ u16 Bs[128 * 64];   // 16 KB

    const int n0 = blockIdx.x * 128;
    const int m0 = blockIdx.y * 64;

    const int tid  = threadIdx.x;
    const int lane = tid & 63;
    const int wv   = tid >> 6;
    const int l15  = lane & 15;
    const int q4   = lane >> 4;
    const int wm   = (wv >> 1) * 32;
    const int wn   = (wv & 1) * 64;

    f32x4 acc[2][4] = {};

    for (int kk = 0; kk < CDIM; kk += 64) {
        __syncthreads();
#pragma unroll
        for (int ch = 0; ch < 4; ++ch) {
            const int f = (ch * 256 + tid) * 8;
            const int r = f >> 6;
            const int c = (f ^ ((r & 7) << 3)) & 63;
            const int lb = (ch * 256 + wv * 64) * 8;
            gload_lds16(Wo + (size_t)(n0 + r) * CDIM + kk + c, Bs + lb);
            if (ch < 2)
                gload_lds16(O + (size_t)(m0 + r) * CDIM + kk + c, As + lb);
        }
        __syncthreads();

#pragma unroll
        for (int ks = 0; ks < 2; ++ks) {
            short8 af[2], bf[4];
#pragma unroll
            for (int t = 0; t < 2; ++t) {
                const int ra = wm + t * 16 + l15;
                af[t] = *(const short8*)(As + ra * 64 +
                        ((ks * 32 + q4 * 8) ^ ((ra & 7) << 3)));
            }
#pragma unroll
            for (int t = 0; t < 4; ++t) {
                const int rb = wn + t * 16 + l15;
                bf[t] = *(const short8*)(Bs + rb * 64 +
                        ((ks * 32 + q4 * 8) ^ ((rb & 7) << 3)));
            }
#pragma unroll
            for (int tm = 0; tm < 2; ++tm)
#pragma unroll
                for (int tn = 0; tn < 4; ++tn)
                    acc[tm][tn] = mfma16(af[tm], bf[tn], acc[tm][tn]);
        }
    }

#pragma unroll
    for (int tm = 0; tm < 2; ++tm) {
#pragma unroll
        for (int tn = 0; tn < 4; ++tn) {
            const int col = n0 + wn + tn * 16 + l15;
            const float bb = bias[col];
#pragma unroll
            for (int r = 0; r < 4; ++r) {
                const int row = m0 + wm + tm * 16 + q4 * 4 + r;
                out[(size_t)row * CDIM + col] = acc[tm][tn][r] + bb;  // fp32
            }
        }
    }
}

extern "C" void kernel_launch(void* const* d_in, const int* in_sizes, int n_in,
                              void* d_out, int out_size, void* d_ws, size_t ws_size,
                              hipStream_t stream)
{
    const float* x  = (const float*)d_in[0];
    const float* Wk = (const float*)d_in[1];
    const float* Wq = (const float*)d_in[2];
    const float* Wv = (const float*)d_in[3];
    const float* Wo = (const float*)d_in[4];
    const float* bo = (const float*)d_in[5];
    float* out = (float*)d_out;

    // ws layout (u16): xb + 4 weights + K + Q + O  = 51.5 MB
    const size_t SZ = (size_t)NROW * CDIM;   // 6,291,456
    const size_t WZ = (size_t)CDIM * CDIM;   //   147,456
    u16* xb  = (u16*)d_ws;
    u16* Wkb = xb  + SZ;
    u16* Wqb = Wkb + WZ;
    u16* Wvb = Wqb + WZ;
    u16* Wob = Wvb + WZ;
    u16* Kw  = Wob + WZ;
    u16* Qw  = Kw + SZ;
    u16* Ow  = Qw + SZ;
    u16* VTw = (u16*)d_out;   // V^T [B,H,D,T] scratch in d_out

    cvt_all<<<dim3(3360), 256, 0, stream>>>(
        x, Wk, Wq, Wv, Wo, xb, Wkb, Wqb, Wvb, Wob);

    gemm_qkv<<<dim3(1152), 256, 0, stream>>>(xb, Wkb, Wvb, Wqb, Kw, VTw, Qw);

    dim3 g2(4, BATCH * NHEAD);
    attn_kernel<<<g2, 256, 0, stream>>>(Qw, Kw, VTw, Ow);

    dim3 g3(CDIM / 128, NROW / 64);
    gemm_out<<<g3, 256, 0, stream>>>(Ow, Wob, bo, out);
}